// Round 16
// baseline (7149.155 us; speedup 1.0000x reference)
//
#include <hip/hip_runtime.h>
#include <hip/hip_bf16.h>

static constexpr int C  = 21;
static constexpr int H  = 384;
static constexpr int W  = 384;
static constexpr int HW = H * W;
static constexpr float NCLIQ = 5.0f;
static constexpr int GRID = 1024;       // co-residency-guaranteed persistent grid

typedef unsigned short u16;
typedef unsigned int   u32;

// function-local constexpr taps: exp(-o^2/18), o=-6..6 — folds to immediates
#define GKDEF constexpr float gk[13] = { \
    0.13533528f, 0.24935222f, 0.41111229f, 0.60653066f, 0.80073740f, \
    0.94595947f, 1.00000000f, 0.94595947f, 0.80073740f, 0.60653066f, \
    0.41111229f, 0.24935222f, 0.13533528f }

__device__ __forceinline__ float bfu2f(u16 u) {
    return __uint_as_float(((u32)u) << 16);
}
__device__ __forceinline__ u16 f2bfu(float f) {
    unsigned x = __float_as_uint(f);
    return (u16)((x + 0x7FFF + ((x >> 16) & 1)) >> 16);   // RNE; inputs finite
}

// device-scope grid barrier: 1 arrival per block, acquire-spin by thread 0.
// Safe because GRID=1024 < guaranteed capacity 1792 (see launch_bounds note).
__device__ __forceinline__ void gridbar(u32* ctr, u32 target) {
    __threadfence();          // all this block's writes visible device-wide
    __syncthreads();
    if (threadIdx.x == 0) {
        __hip_atomic_fetch_add(ctr, 1u, __ATOMIC_ACQ_REL, __HIP_MEMORY_SCOPE_AGENT);
        while (__hip_atomic_load(ctr, __ATOMIC_ACQUIRE, __HIP_MEMORY_SCOPE_AGENT) < target)
            __builtin_amdgcn_s_sleep(2);
    }
    __syncthreads();
}

// one persistent kernel: prep+mats | 5 x [ST | VF] | store, barrier-separated.
// __launch_bounds__(256,4): VGPR<=128 => capacity = min(2048thr/256, 160K/21.5K
// LDS, 32w/4w) = 7 blocks/CU -> 1792 co-resident slots >= GRID. No deadlock.
__global__ __launch_bounds__(256, 4)
void k_all(const float* __restrict__ un, const float* __restrict__ rgb,
           const int* __restrict__ sp,
           const float* __restrict__ Wsp, const float* __restrict__ Wbi,
           const float* __restrict__ Cm,
           const float* __restrict__ loww, const float* __restrict__ highw,
           float* __restrict__ q, float* __restrict__ unp,
           u16* __restrict__ wtab, float* __restrict__ msum,
           float* __restrict__ inv_sp, float* __restrict__ inv_bn,
           float* __restrict__ M1, float* __restrict__ M2,
           u16* __restrict__ t1, u16* __restrict__ t2,
           u32* __restrict__ ctr, float* __restrict__ out) {
    GKDEF;
    __shared__ float sh[5376];   // VF: A[2880]+B[1152]; store: l[5376]
    int bid = blockIdx.x;
    u32 bar = 0;

    // ================= phase 0: prep (units 0..575) + mats (unit 576) ======
    for (int u = bid; u <= 576; u += GRID) {
        if (u == 576) {
            for (int i = threadIdx.x; i < C * C; i += 256) {
                int c = i / C, k = i - c * C;
                float a1 = 0.f, a2 = 0.f;
                for (int j = 0; j < C; j++) {
                    float cm = Cm[c * C + j];
                    a1 += cm * Wsp[j * C + k];
                    a2 += cm * Wbi[j * C + k];
                }
                M1[i] = a1;
                M2[i] = a2;
            }
        } else {
            int chunk = (u & 7) * 72 + (u >> 3);    // XCD swizzle
            int p = chunk * 256 + threadIdx.x;
            int y = p / W, x = p - y * W;
            for (int c = 0; c < C; c++) {
                float v = un[p * C + c];
                q[c * HW + p] = v;
                unp[c * HW + p] = v;
            }
            float r0 = rgb[p * 3 + 0];
            float g0 = rgb[p * 3 + 1];
            float b0 = rgb[p * 3 + 2];
            float s = 0.f;
            int t = 0;
            for (int dy = -2; dy <= 2; dy++) {
                for (int dx = -2; dx <= 2; dx++, t++) {
                    int sy = y - dy, sx = x - dx;
                    float wv = 0.f;
                    if (sy >= 0 && sy < H && sx >= 0 && sx < W) {
                        int o = sy * W + sx;
                        float dr = r0 - rgb[o * 3 + 0];
                        float dg = g0 - rgb[o * 3 + 1];
                        float db = b0 - rgb[o * 3 + 2];
                        wv = expf(-(float)(dy * dy + dx * dx) * (1.0f / 51200.0f)) *
                             expf(-(dr * dr + dg * dg + db * db) * (1.0f / 18.0f));
                    }
                    u16 wu = f2bfu(wv);
                    wtab[(size_t)t * HW + p] = wu;
                    s += bfu2f(wu);
                }
            }
            inv_bn[p] = 1.0f / s;
            float fy = 0.f, fx = 0.f;
            for (int o = -6; o <= 6; o++) {
                if (y - o >= 0 && y - o < H) fy += gk[o + 6];
                if (x - o >= 0 && x - o < W) fx += gk[o + 6];
            }
            inv_sp[p] = 1.0f / (fy * fx);
            int vv = sp[x * W + y];   // sp_map transposed: sp[x][y]
            msum[p] = (vv == 5 || vv == 37 || vv == 81 || vv == 150 || vv == 230)
                          ? 1.0f : 0.0f;
        }
    }
    bar++; gridbar(ctr, GRID * bar);

    // ================= 5 iterations =======================================
    for (int it = 0; it < 5; it++) {
        // ---- ST: softmax + both 21x21 matmuls (units 0..575) ----
        for (int u = bid; u < 576; u += GRID) {
            int chunk = (u & 7) * 72 + (u >> 3);
            int p = chunk * 256 + threadIdx.x;
            float v[C];
            float mx = -1e30f;
#pragma unroll
            for (int c = 0; c < C; c++) {
                v[c] = q[c * HW + p];
                mx = fmaxf(mx, v[c]);
            }
            float s = 0.f;
#pragma unroll
            for (int c = 0; c < C; c++) {
                v[c] = expf(v[c] - mx);
                s += v[c];
            }
            float inv = 1.0f / s;
            float a1[C], a2[C];
#pragma unroll
            for (int c = 0; c < C; c++) { a1[c] = 0.f; a2[c] = 0.f; }
#pragma unroll
            for (int k = 0; k < C; k++) {
                float e = v[k];
#pragma unroll
                for (int c = 0; c < C; c++) {
                    a1[c] += M1[c * C + k] * e;   // uniform index -> s_load
                    a2[c] += M2[c * C + k] * e;
                }
            }
#pragma unroll
            for (int c = 0; c < C; c++) {
                t1[c * HW + p] = f2bfu(a1[c] * inv);
                t2[c * HW + p] = f2bfu(a2[c] * inv);
            }
        }
        bar++; gridbar(ctr, GRID * bar);

        // ---- VF: LDS-tiled separable blur + bilateral + update (0..3023) ----
        for (int u = bid; u < 3024; u += GRID) {
            float* A = sh;            // 20*144
            float* B = sh + 2880;     // 8*144
            int xcd = u & 7;
            int idx = u >> 3;
            int c   = idx % 21;
            int rem = idx / 21;
            int xt  = rem % 3;
            int ytl = rem / 3;
            int gyt = xcd * 6 + ytl;
            int x0 = xt * 128;
            int y0 = gyt * 8;
            const u16* t1p = t1 + (size_t)c * HW;

            for (int i = threadIdx.x; i < 20 * 36; i += 256) {
                int r = i / 36, q4 = i - r * 36;
                int gy = y0 - 6 + r;
                int gx = x0 - 8 + q4 * 4;
                float4 v;
                if (gy < 0 || gy >= H) {
                    v.x = v.y = v.z = v.w = 0.f;
                } else if (gx >= 0 && gx + 3 < W) {
                    ushort4 uu = *(const ushort4*)(t1p + gy * W + gx);
                    v.x = bfu2f(uu.x); v.y = bfu2f(uu.y);
                    v.z = bfu2f(uu.z); v.w = bfu2f(uu.w);
                } else {
                    float e[4];
                    for (int j = 0; j < 4; j++) {
                        int xx = gx + j;
                        e[j] = (xx >= 0 && xx < W) ? bfu2f(t1p[gy * W + xx]) : 0.f;
                    }
                    v.x = e[0]; v.y = e[1]; v.z = e[2]; v.w = e[3];
                }
                *(float4*)(A + r * 144 + q4 * 4) = v;
            }
            __syncthreads();

            for (int i = threadIdx.x; i < 8 * 144; i += 256) {
                int r = i / 144, col = i - r * 144;
                float a = 0.f;
                for (int d = 0; d < 13; d++) a += gk[d] * A[(r + d) * 144 + col];
                B[i] = a;
            }
            __syncthreads();

            int row = threadIdx.x >> 5;
            int xq  = (threadIdx.x & 31) * 4;
            int y   = y0 + row;
            int x4  = x0 + xq;
            int p4  = y * W + x4;

            float bw[16];
            for (int i = 0; i < 16; i++) bw[i] = B[row * 144 + xq + 2 + i];
            float sp_[4];
            for (int j = 0; j < 4; j++) {
                float a = 0.f;
                for (int t = 0; t < 13; t++) a += gk[t] * bw[j + t];
                sp_[j] = a;
            }

            float bi[4] = {0.f, 0.f, 0.f, 0.f};
            const u16* t2p = t2 + (size_t)c * HW;
            int t = 0;
            for (int dy = -2; dy <= 2; dy++) {
                int sy = min(max(y - dy, 0), H - 1);
                const u16* rowp = t2p + sy * W;
                float r[12];
                for (int i = 0; i < 3; i++) {
                    int bx = x4 - 4 + 4 * i;
                    int bc = min(max(bx, 0), W - 4);
                    ushort4 uu = *(const ushort4*)(rowp + bc);
                    r[4 * i + 0] = bfu2f(uu.x); r[4 * i + 1] = bfu2f(uu.y);
                    r[4 * i + 2] = bfu2f(uu.z); r[4 * i + 3] = bfu2f(uu.w);
                }
                for (int dx = -2; dx <= 2; dx++, t++) {
                    ushort4 wu = *(const ushort4*)(wtab + (size_t)t * HW + p4);
                    bi[0] += bfu2f(wu.x) * r[0 - dx + 4];
                    bi[1] += bfu2f(wu.y) * r[1 - dx + 4];
                    bi[2] += bfu2f(wu.z) * r[2 - dx + 4];
                    bi[3] += bfu2f(wu.w) * r[3 - dx + 4];
                }
            }

            float lc = loww[c], hw_ = highw[0];
            float4 msv = *(const float4*)(msum + p4);
            float4 isv = *(const float4*)(inv_sp + p4);
            float4 ibv = *(const float4*)(inv_bn + p4);
            float4 unv = *(const float4*)(unp + (size_t)c * HW + p4);
            float* qp = q + (size_t)c * HW + p4;
            float4 qo4 = *(const float4*)qp;
            float msa[4] = {msv.x, msv.y, msv.z, msv.w};
            float isa[4] = {isv.x, isv.y, isv.z, isv.w};
            float iba[4] = {ibv.x, ibv.y, ibv.z, ibv.w};
            float qoa[4] = {qo4.x, qo4.y, qo4.z, qo4.w};
            float una[4] = {unv.x, unv.y, unv.z, unv.w};
            float outv[4];
            for (int j = 0; j < 4; j++) {
                float pw = sp_[j] * isa[j] + bi[j] * iba[j];
                float qo = qoa[j];
                float ft = (msa[j] * qo + (NCLIQ - msa[j])) / qo;
                float su = lc * ft + hw_ * (1.0f - ft);
                outv[j] = una[j] - pw + su;
            }
            float4 res;
            res.x = outv[0]; res.y = outv[1]; res.z = outv[2]; res.w = outv[3];
            *(float4*)qp = res;
            __syncthreads();   // A/B reuse safety before next unit
        }
        bar++; gridbar(ctr, GRID * bar);
    }

    // ================= store: q (C,H,W) -> out (H,W,C) =====================
    for (int u = bid; u < 576; u += GRID) {
        int chunk = (u & 7) * 72 + (u >> 3);
        int p0 = chunk * 256;
        for (int c = 0; c < C; c++)
            sh[threadIdx.x * C + c] = q[c * HW + p0 + threadIdx.x];
        __syncthreads();
        float* dst = out + (size_t)p0 * C;
        for (int i = threadIdx.x; i < 256 * C; i += 256) dst[i] = sh[i];
        __syncthreads();
    }
}

// ---- launch -----------------------------------------------------------------

extern "C" void kernel_launch(void* const* d_in, const int* in_sizes, int n_in,
                              void* d_out, int out_size, void* d_ws, size_t ws_size,
                              hipStream_t stream) {
    const float* un    = (const float*)d_in[0];
    const float* rgb   = (const float*)d_in[1];
    const int*   sp    = (const int*)d_in[2];
    const float* Wsp   = (const float*)d_in[3];
    const float* Wbi   = (const float*)d_in[4];
    const float* Cm    = (const float*)d_in[5];
    const float* loww  = (const float*)d_in[6];
    const float* highw = (const float*)d_in[7];
    float* out = (float*)d_out;

    // ws layout ~46.6 MB + barrier counter at +64 MiB (ws is ~256 MiB)
    float* ws    = (float*)d_ws;
    float* q     = ws;                            // C*HW fp32
    float* unp   = q   + (size_t)C * HW;          // C*HW fp32
    float* msum  = unp + (size_t)C * HW;          // HW
    float* isp   = msum + HW;                     // HW
    float* ibn   = isp + HW;                      // HW
    float* M1    = ibn + HW;                      // C*C
    float* M2    = M1 + C * C;                    // C*C
    u16*   t1    = (u16*)(M2 + C * C + 6);        // C*HW bf16 (8B-aligned)
    u16*   t2    = t1 + (size_t)C * HW;           // C*HW bf16
    u16*   wtab  = t2 + (size_t)C * HW;           // 25*HW bf16
    u32*   ctr   = (u32*)((char*)d_ws + (size_t)64 * 1024 * 1024);

    hipMemsetAsync(ctr, 0, 256, stream);          // zero barrier counter
    k_all<<<GRID, 256, 0, stream>>>(un, rgb, sp, Wsp, Wbi, Cm, loww, highw,
                                    q, unp, wtab, msum, isp, ibn, M1, M2,
                                    t1, t2, ctr, out);
}

// Round 18
// 276.712 us; speedup vs baseline: 25.8361x; 25.8361x over previous
//
#include <hip/hip_runtime.h>
#include <hip/hip_bf16.h>

static constexpr int C  = 21;
static constexpr int H  = 384;
static constexpr int W  = 384;
static constexpr int HW = H * W;
static constexpr float NCLIQ = 5.0f;

typedef unsigned short u16;
typedef unsigned int   u32;

// function-local constexpr taps: exp(-o^2/18), o=-6..6 — folds to immediates
#define GKDEF constexpr float gk[13] = { \
    0.13533528f, 0.24935222f, 0.41111229f, 0.60653066f, 0.80073740f, \
    0.94595947f, 1.00000000f, 0.94595947f, 0.80073740f, 0.60653066f, \
    0.41111229f, 0.24935222f, 0.13533528f }

__device__ __forceinline__ float bfu2f(u16 u) {
    return __uint_as_float(((u32)u) << 16);
}
__device__ __forceinline__ u16 f2bfu(float f) {
    unsigned x = __float_as_uint(f);
    return (u16)((x + 0x7FFF + ((x >> 16) & 1)) >> 16);   // RNE; inputs finite
}

// ---- prep: q/un planar + wtab + norms + msum + M1/M2 + fused ST(iter 0) ----
__global__ __launch_bounds__(256)
void k_prep(const float* __restrict__ un, const float* __restrict__ rgb,
            const int* __restrict__ sp,
            const float* __restrict__ Wsp, const float* __restrict__ Wbi,
            const float* __restrict__ Cm,
            float* __restrict__ q, float* __restrict__ unp,
            u16* __restrict__ wtab, float* __restrict__ msum,
            float* __restrict__ inv_sp, float* __restrict__ inv_bn,
            float* __restrict__ M1, float* __restrict__ M2,
            u16* __restrict__ t1, u16* __restrict__ t2) {
    GKDEF;
    __shared__ float sM1[C * C], sM2[C * C];
    // every block computes M = Cm@W itself (no cross-block race); block 0
    // also publishes the global copy for the later k_ST dispatches
    for (int i = threadIdx.x; i < C * C; i += 256) {
        int c = i / C, k = i - c * C;
        float a1 = 0.f, a2 = 0.f;
        for (int j = 0; j < C; j++) {
            float cm = Cm[c * C + j];
            a1 += cm * Wsp[j * C + k];
            a2 += cm * Wbi[j * C + k];
        }
        sM1[i] = a1;
        sM2[i] = a2;
        if (blockIdx.x == 0) { M1[i] = a1; M2[i] = a2; }
    }

    int bid = blockIdx.x;                       // 576, XCD-swizzled
    int chunk = (bid & 7) * 72 + (bid >> 3);
    int p = chunk * 256 + threadIdx.x;
    int y = p / W, x = p - y * W;

    float v[C];
    for (int c = 0; c < C; c++) {
        v[c] = un[p * C + c];
        q[c * HW + p] = v[c];
        unp[c * HW + p] = v[c];
    }

    // bilateral weights (bf16-rounded); denominator sums the SAME rounded vals
    float r0 = rgb[p * 3 + 0];
    float g0 = rgb[p * 3 + 1];
    float b0 = rgb[p * 3 + 2];
    float s = 0.f;
    int t = 0;
    for (int dy = -2; dy <= 2; dy++) {
        for (int dx = -2; dx <= 2; dx++, t++) {
            int sy = y - dy, sx = x - dx;
            float wv = 0.f;
            if (sy >= 0 && sy < H && sx >= 0 && sx < W) {
                int o = sy * W + sx;
                float dr = r0 - rgb[o * 3 + 0];
                float dg = g0 - rgb[o * 3 + 1];
                float db = b0 - rgb[o * 3 + 2];
                wv = expf(-(float)(dy * dy + dx * dx) * (1.0f / 51200.0f)) *
                     expf(-(dr * dr + dg * dg + db * db) * (1.0f / 18.0f));
            }
            u16 wu = f2bfu(wv);
            wtab[(size_t)t * HW + p] = wu;
            s += bfu2f(wu);
        }
    }
    inv_bn[p] = 1.0f / s;

    float fy = 0.f, fx = 0.f;
    for (int o = -6; o <= 6; o++) {
        if (y - o >= 0 && y - o < H) fy += gk[o + 6];
        if (x - o >= 0 && x - o < W) fx += gk[o + 6];
    }
    inv_sp[p] = 1.0f / (fy * fx);

    int vv = sp[x * W + y];   // sp_map transposed: sp[x][y]
    msum[p] = (vv == 5 || vv == 37 || vv == 81 || vv == 150 || vv == 230) ? 1.0f : 0.0f;

    // ---- fused ST for iteration 0: softmax(v) + M@sm -> t1,t2 ----
    __syncthreads();          // sM ready
    float mx = -1e30f;
#pragma unroll
    for (int c = 0; c < C; c++) mx = fmaxf(mx, v[c]);
    float ssum = 0.f;
#pragma unroll
    for (int c = 0; c < C; c++) {
        v[c] = expf(v[c] - mx);
        ssum += v[c];
    }
    float inv = 1.0f / ssum;
    float a1[C], a2[C];
#pragma unroll
    for (int c = 0; c < C; c++) { a1[c] = 0.f; a2[c] = 0.f; }
#pragma unroll
    for (int k = 0; k < C; k++) {
        float e = v[k];
#pragma unroll
        for (int c = 0; c < C; c++) {
            a1[c] += sM1[c * C + k] * e;
            a2[c] += sM2[c * C + k] * e;
        }
    }
#pragma unroll
    for (int c = 0; c < C; c++) {
        t1[c * HW + p] = f2bfu(a1[c] * inv);
        t2[c * HW + p] = f2bfu(a2[c] * inv);
    }
}

// fused softmax + both 21x21 matmuls (iters 1..4). M via uniform s_loads.
__global__ __launch_bounds__(256)
void k_ST(const float* __restrict__ q, const float* __restrict__ M1,
          const float* __restrict__ M2,
          u16* __restrict__ t1, u16* __restrict__ t2) {
    int bid = blockIdx.x;                  // 576, XCD-swizzled
    int chunk = (bid & 7) * 72 + (bid >> 3);
    int p = chunk * 256 + threadIdx.x;
    float v[C];
    float mx = -1e30f;
#pragma unroll
    for (int c = 0; c < C; c++) {
        v[c] = q[c * HW + p];
        mx = fmaxf(mx, v[c]);
    }
    float s = 0.f;
#pragma unroll
    for (int c = 0; c < C; c++) {
        v[c] = expf(v[c] - mx);
        s += v[c];
    }
    float inv = 1.0f / s;
    float a1[C], a2[C];
#pragma unroll
    for (int c = 0; c < C; c++) { a1[c] = 0.f; a2[c] = 0.f; }
#pragma unroll
    for (int k = 0; k < C; k++) {
        float e = v[k];
#pragma unroll
        for (int c = 0; c < C; c++) {
            a1[c] += M1[c * C + k] * e;   // uniform index -> s_load
            a2[c] += M2[c * C + k] * e;
        }
    }
#pragma unroll
    for (int c = 0; c < C; c++) {
        t1[c * HW + p] = f2bfu(a1[c] * inv);
        t2[c * HW + p] = f2bfu(a2[c] * inv);
    }
}

// fused separable blur (LDS) + bilateral (t2 LDS-staged) + update.
// XCD-swizzled; last iteration writes out (H,W,C) directly and skips q.
__global__ __launch_bounds__(256)
void k_VF(const u16* __restrict__ t1, const u16* __restrict__ t2,
          const u16* __restrict__ wtab, const float* __restrict__ msum,
          const float* __restrict__ inv_sp, const float* __restrict__ inv_bn,
          const float* __restrict__ unp,
          const float* __restrict__ loww, const float* __restrict__ highw,
          float* __restrict__ q, float* __restrict__ outp) {
    GKDEF;
    __shared__ float A[20 * 144];   // t1 halo tile; later reused for t2 tile
    __shared__ float B[8 * 144];    // blurV output
    int bid = blockIdx.x;                  // grid 3024
    int xcd = bid & 7;
    int idx = bid >> 3;
    int c   = idx % 21;
    int rem = idx / 21;
    int xt  = rem % 3;
    int ytl = rem / 3;
    int gyt = xcd * 6 + ytl;
    int x0 = xt * 128;
    int y0 = gyt * 8;
    const u16* t1p = t1 + (size_t)c * HW;

    // ---- stage A = t1 halo (zero-padded), bf16 -> fp32 ----
    for (int i = threadIdx.x; i < 20 * 36; i += 256) {
        int r = i / 36, q4 = i - r * 36;
        int gy = y0 - 6 + r;
        int gx = x0 - 8 + q4 * 4;
        float4 v;
        if (gy < 0 || gy >= H) {
            v.x = v.y = v.z = v.w = 0.f;
        } else if (gx >= 0 && gx + 3 < W) {
            ushort4 u = *(const ushort4*)(t1p + gy * W + gx);
            v.x = bfu2f(u.x); v.y = bfu2f(u.y); v.z = bfu2f(u.z); v.w = bfu2f(u.w);
        } else {
            float e[4];
            for (int j = 0; j < 4; j++) {
                int xx = gx + j;
                e[j] = (xx >= 0 && xx < W) ? bfu2f(t1p[gy * W + xx]) : 0.f;
            }
            v.x = e[0]; v.y = e[1]; v.z = e[2]; v.w = e[3];
        }
        *(float4*)(A + r * 144 + q4 * 4) = v;
    }
    __syncthreads();

    // ---- blurV: B[r][col] = sum_d gk[d] * A[r+d][col] ----
    for (int i = threadIdx.x; i < 8 * 144; i += 256) {
        int r = i / 144, col = i - r * 144;
        float a = 0.f;
        for (int d = 0; d < 13; d++) a += gk[d] * A[(r + d) * 144 + col];
        B[i] = a;
    }
    __syncthreads();

    int row = threadIdx.x >> 5;
    int xq  = (threadIdx.x & 31) * 4;
    int y   = y0 + row;
    int x4  = x0 + xq;
    int p4  = y * W + x4;

    // horizontal 13-tap from LDS B (A no longer needed -> will be reused)
    float bw[16];
    for (int i = 0; i < 16; i++) bw[i] = B[row * 144 + xq + 2 + i];
    float sp_[4];
    for (int j = 0; j < 4; j++) {
        float a = 0.f;
        for (int t = 0; t < 13; t++) a += gk[t] * bw[j + t];
        sp_[j] = a;
    }

    // ---- stage t2 tile into A (rows y0-2..y0+9, cols x0-8..x0+135) ----
    const u16* t2p = t2 + (size_t)c * HW;
    for (int i = threadIdx.x; i < 12 * 36; i += 256) {
        int r = i / 36, q4 = i - r * 36;
        int gy = min(max(y0 - 2 + r, 0), H - 1);        // clamped; OOB weight 0
        int gx = min(max(x0 - 8 + q4 * 4, 0), W - 4);   // clamped; OOB weight 0
        ushort4 u = *(const ushort4*)(t2p + gy * W + gx);
        float4 v;
        v.x = bfu2f(u.x); v.y = bfu2f(u.y); v.z = bfu2f(u.z); v.w = bfu2f(u.w);
        *(float4*)(A + r * 144 + q4 * 4) = v;
    }
    __syncthreads();

    // ---- bilateral from LDS (weights still bf16 from global, coalesced) ----
    float bi[4] = {0.f, 0.f, 0.f, 0.f};
    int lb = xq + 8;                        // local col of x4 in the 144-tile
    int t = 0;
    for (int dy = -2; dy <= 2; dy++) {
        int r = row - dy + 2;               // 0..11
        float rr[12];
        float4 v0 = *(const float4*)(A + r * 144 + lb - 4);
        float4 v1 = *(const float4*)(A + r * 144 + lb);
        float4 v2 = *(const float4*)(A + r * 144 + lb + 4);
        rr[0] = v0.x; rr[1] = v0.y; rr[2]  = v0.z; rr[3]  = v0.w;
        rr[4] = v1.x; rr[5] = v1.y; rr[6]  = v1.z; rr[7]  = v1.w;
        rr[8] = v2.x; rr[9] = v2.y; rr[10] = v2.z; rr[11] = v2.w;
        for (int dx = -2; dx <= 2; dx++, t++) {
            ushort4 wu = *(const ushort4*)(wtab + (size_t)t * HW + p4);
            bi[0] += bfu2f(wu.x) * rr[0 - dx + 4];
            bi[1] += bfu2f(wu.y) * rr[1 - dx + 4];
            bi[2] += bfu2f(wu.z) * rr[2 - dx + 4];
            bi[3] += bfu2f(wu.w) * rr[3 - dx + 4];
        }
    }

    // ---- update: q/out = un - pairwise + superpixel closed form ----
    float lc = loww[c], hw_ = highw[0];
    float4 msv = *(const float4*)(msum + p4);
    float4 isv = *(const float4*)(inv_sp + p4);
    float4 ibv = *(const float4*)(inv_bn + p4);
    float4 unv = *(const float4*)(unp + (size_t)c * HW + p4);
    float* qp = q + (size_t)c * HW + p4;
    float4 qo4 = *(const float4*)qp;
    float msa[4] = {msv.x, msv.y, msv.z, msv.w};
    float isa[4] = {isv.x, isv.y, isv.z, isv.w};
    float iba[4] = {ibv.x, ibv.y, ibv.z, ibv.w};
    float qoa[4] = {qo4.x, qo4.y, qo4.z, qo4.w};
    float una[4] = {unv.x, unv.y, unv.z, unv.w};
    float outv[4];
    for (int j = 0; j < 4; j++) {
        float pw = sp_[j] * isa[j] + bi[j] * iba[j];
        float qo = qoa[j];
        float ft = (msa[j] * qo + (NCLIQ - msa[j])) / qo;
        float su = lc * ft + hw_ * (1.0f - ft);
        outv[j] = una[j] - pw + su;
    }
    if (outp) {   // last iteration: write final (H,W,C) layout directly
        for (int j = 0; j < 4; j++) outp[(size_t)(p4 + j) * C + c] = outv[j];
    } else {
        float4 res;
        res.x = outv[0]; res.y = outv[1]; res.z = outv[2]; res.w = outv[3];
        *(float4*)qp = res;
    }
    __syncthreads();   // LDS safety (no-op cost; single unit per block)
}

// ---- launch -----------------------------------------------------------------

extern "C" void kernel_launch(void* const* d_in, const int* in_sizes, int n_in,
                              void* d_out, int out_size, void* d_ws, size_t ws_size,
                              hipStream_t stream) {
    const float* un    = (const float*)d_in[0];
    const float* rgb   = (const float*)d_in[1];
    const int*   sp    = (const int*)d_in[2];
    const float* Wsp   = (const float*)d_in[3];
    const float* Wbi   = (const float*)d_in[4];
    const float* Cm    = (const float*)d_in[5];
    const float* loww  = (const float*)d_in[6];
    const float* highw = (const float*)d_in[7];
    float* out = (float*)d_out;

    // ws layout ~46.5 MB
    float* ws    = (float*)d_ws;
    float* q     = ws;                            // C*HW fp32
    float* unp   = q   + (size_t)C * HW;          // C*HW fp32
    float* msum  = unp + (size_t)C * HW;          // HW
    float* isp   = msum + HW;                     // HW
    float* ibn   = isp + HW;                      // HW
    float* M1    = ibn + HW;                      // C*C
    float* M2    = M1 + C * C;                    // C*C
    u16*   t1    = (u16*)(M2 + C * C + 6);        // C*HW bf16 (8B-aligned)
    u16*   t2    = t1 + (size_t)C * HW;           // C*HW bf16
    u16*   wtab  = t2 + (size_t)C * HW;           // 25*HW bf16

    dim3 blk(256);
    dim3 gpix(HW / 256);                 // 576
    dim3 gVF(3 * 48 * C);                // 3024, 1-D swizzled

    // prep includes iteration 0's ST
    k_prep<<<gpix, blk, 0, stream>>>(un, rgb, sp, Wsp, Wbi, Cm,
                                     q, unp, wtab, msum, isp, ibn, M1, M2,
                                     t1, t2);
    for (int it = 0; it < 5; it++) {
        k_VF<<<gVF, blk, 0, stream>>>(t1, t2, wtab, msum, isp, ibn,
                                      unp, loww, highw, q,
                                      (it == 4) ? out : (float*)nullptr);
        if (it < 4)
            k_ST<<<gpix, blk, 0, stream>>>(q, M1, M2, t1, t2);
    }
}